// Round 3
// baseline (538.967 us; speedup 1.0000x reference)
//
#include <hip/hip_runtime.h>

#define DMODEL 1024
#define NH 16
#define DK 64
#define NB 4
#define SEQ 2048
#define MTOT (NB*SEQ)

typedef __attribute__((ext_vector_type(8))) short bf16x8;
typedef __attribute__((ext_vector_type(4))) short s16x4;
typedef __attribute__((ext_vector_type(4))) float f32x4;
typedef __attribute__((ext_vector_type(4))) float f4;
typedef __attribute__((ext_vector_type(4))) unsigned short us4;
typedef __attribute__((ext_vector_type(8))) unsigned short us8;
typedef __attribute__((ext_vector_type(2))) unsigned int u32x2;
typedef const __attribute__((address_space(1))) void* as1cv;
typedef __attribute__((address_space(3))) void* as3v;

__device__ __forceinline__ unsigned short f2bf(float f){
  union { float f; unsigned u; } v; v.f = f;
  unsigned r = v.u + 0x7FFFu + ((v.u >> 16) & 1u);   // RNE
  return (unsigned short)(r >> 16);
}

__device__ __forceinline__ unsigned cvt_pk_bf16(float lo, float hi){
  unsigned r;
  asm("v_cvt_pk_bf16_f32 %0, %1, %2" : "=v"(r) : "v"(lo), "v"(hi));
  return r;
}

// K=16 bf16 MFMA: A[row=lane&15][k=(lane>>4)*4+j], B[k=(lane>>4)*4+j][col=lane&15]
__device__ __forceinline__ f32x4 mfma16(s16x4 a, s16x4 b, f32x4 c){
#if __has_builtin(__builtin_amdgcn_mfma_f32_16x16x16bf16_1k)
  return __builtin_amdgcn_mfma_f32_16x16x16bf16_1k(a, b, c, 0, 0, 0);
#else
  asm("v_mfma_f32_16x16x16_bf16 %0, %1, %2, %0" : "+v"(c) : "v"(a), "v"(b));
  return c;
#endif
}

// ---------------- fp32 -> bf16 convert (weights) ----------------
__global__ __launch_bounds__(256) void cvt_kernel(const float* __restrict__ src,
                                                  unsigned short* __restrict__ dst, int n4){
  int i = blockIdx.x*256 + threadIdx.x;
  if (i >= n4) return;
  f4 f = ((const f4*)src)[i];
  us4 o;
  o.x = f2bf(f.x); o.y = f2bf(f.y); o.z = f2bf(f.z); o.w = f2bf(f.w);
  ((us4*)dst)[i] = o;
}

// ---------------- GEMM: C = A @ B^T + bias ----------------
// A: [M=8192, K=1024] fp32 (AF32=1, reg-staged+converted) or bf16 (AF32=0, global_load_lds)
// B: [N=1024, K=1024] bf16 (torch Linear weight layout)
// MODE 0: dst bf16 in [B,H,S,DK] layout, value = (acc+bias)*scale
// MODE 1: dst bf16 in [B,H,DK,S] (transposed) layout, value = acc + bias
// MODE 2: dst fp32 [M, N], value = acc + bias
template<int MODE, int AF32>
__global__ __launch_bounds__(256) void gemm_bt(const void* __restrict__ Aptr,
    const unsigned short* __restrict__ Bw, const float* __restrict__ bias,
    void* __restrict__ dst, float scale)
{
  __shared__ __align__(16) unsigned short sA[128*32];
  __shared__ __align__(16) unsigned short sB[128*32];
  const int tid = threadIdx.x;
  const int lane = tid & 63;
  const int w = tid >> 6;
  const int m0 = blockIdx.y * 128;
  const int n0 = blockIdx.x * 128;
  const int fr = lane & 15;
  const int kg = lane >> 4;
  const int msub = (w & 1) * 64;
  const int nsub = (w >> 1) * 64;

  f32x4 acc[4][4];
#pragma unroll
  for (int i = 0; i < 4; i++)
#pragma unroll
    for (int j = 0; j < 4; j++) acc[i][j] = f32x4{0.f,0.f,0.f,0.f};

  for (int kt = 0; kt < DMODEL; kt += 32){
#pragma unroll
    for (int j = 0; j < 2; j++){
      const int idx = j*256 + tid;
      const int row = idx >> 2;
      const int cg  = (idx & 3) << 3;
      if (AF32){
        const float* ap = (const float*)Aptr + (size_t)(m0+row)*DMODEL + kt + cg;
        f4 f0 = *(const f4*)ap;
        f4 f1 = *(const f4*)(ap + 4);
        us8 o;
        o[0]=f2bf(f0.x); o[1]=f2bf(f0.y); o[2]=f2bf(f0.z); o[3]=f2bf(f0.w);
        o[4]=f2bf(f1.x); o[5]=f2bf(f1.y); o[6]=f2bf(f1.z); o[7]=f2bf(f1.w);
        *((us8*)sA + idx) = o;
      } else {
        const unsigned short* ap = (const unsigned short*)Aptr + (size_t)(m0+row)*DMODEL + kt + cg;
        __builtin_amdgcn_global_load_lds((as1cv)ap, (as3v)(&sA[(size_t)idx*8]), 16, 0, 0);
      }
      const unsigned short* bp = Bw + (size_t)(n0+row)*DMODEL + kt + cg;
      __builtin_amdgcn_global_load_lds((as1cv)bp, (as3v)(&sB[(size_t)idx*8]), 16, 0, 0);
    }
    __syncthreads();
    bf16x8 af[4], bfr[4];
#pragma unroll
    for (int f = 0; f < 4; f++)
      af[f] = *(const bf16x8*)&sA[(msub + f*16 + fr)*32 + kg*8];
#pragma unroll
    for (int f = 0; f < 4; f++)
      bfr[f] = *(const bf16x8*)&sB[(nsub + f*16 + fr)*32 + kg*8];
#pragma unroll
    for (int i = 0; i < 4; i++)
#pragma unroll
      for (int j = 0; j < 4; j++)
        acc[i][j] = __builtin_amdgcn_mfma_f32_16x16x32_bf16(af[i], bfr[j], acc[i][j], 0, 0, 0);
    __syncthreads();
  }

  // epilogue: C/D layout col = lane&15, row = (lane>>4)*4 + r  [m89-verified]
#pragma unroll
  for (int i = 0; i < 4; i++){
#pragma unroll
    for (int j = 0; j < 4; j++){
      const int n = n0 + nsub + j*16 + fr;
      const float bv = bias[n];
      if (MODE == 1){
        // V^T layout: [(b*NH+h)*DK + d][s], 4 consecutive s per lane -> us4 store
        const int m = m0 + msub + i*16 + kg*4;
        const int b = m >> 11, s = m & (SEQ-1);
        const int h = n >> 6,  d = n & (DK-1);
        us4 pk;
#pragma unroll
        for (int r = 0; r < 4; r++) pk[r] = f2bf(acc[i][j][r] + bv);
        *(us4*)&((unsigned short*)dst)[((size_t)(b*NH+h)*DK + d)*SEQ + s] = pk;
      } else {
#pragma unroll
        for (int r = 0; r < 4; r++){
          const int m = m0 + msub + i*16 + kg*4 + r;
          float vacc = acc[i][j][r] + bv;
          if (MODE == 2){
            ((float*)dst)[(size_t)m*DMODEL + n] = vacc;
          } else {
            const int b = m >> 11, s = m & (SEQ-1);
            const int h = n >> 6,  d = n & (DK-1);
            ((unsigned short*)dst)[((size_t)(b*NH + h)*SEQ + s)*DK + d] = f2bf(vacc * scale);
          }
        }
      }
    }
  }
}

// ---------------- flash attention (LDS-free, barrier-free, no cross-lane P) ----------------
// grid 1024 blocks x 256 threads = 4 independent waves; wave owns 32 q-rows (2 subtiles).
// Q pre-scaled by log2(e)/sqrt(DK). K in [B,H,S,DK] bf16; V^T in [B,H,DK,S] bf16.
// Swapped QK^T (mfma(K,Q)): lane holds S^T: q = lane&15, key = n*16 + (lane>>4)*4 + r.
// That register layout IS the A-fragment of mfma_16x16x16, so PV needs no redistribution.
__global__ __launch_bounds__(256) void attn_kernel(const unsigned short* __restrict__ Qh,
    const unsigned short* __restrict__ Kh, const unsigned short* __restrict__ VTh,
    unsigned short* __restrict__ attnO)
{
  const int tid = threadIdx.x;
  const int lane = tid & 63;
  const int w = tid >> 6;
  const int fr = lane & 15;
  const int kg = lane >> 4;
  // XCD-aware swizzle (bijective: 1024 % 8 == 0)
  const int bid = blockIdx.x;
  const int swz = (bid & 7) * 128 + (bid >> 3);
  const int bh = swz >> 4;                 // 16 blocks per (b,h)
  const int qt = (swz & 15) * 128 + w * 32;

  const unsigned short* Qb = Qh + ((size_t)bh*SEQ + qt)*DK;
  const unsigned short* Kb = Kh + (size_t)bh*SEQ*DK + (size_t)fr*DK + kg*8;
  const unsigned short* Vb = VTh + (size_t)bh*DK*SEQ + kg*4;

  bf16x8 qf[2][2];
#pragma unroll
  for (int qh = 0; qh < 2; qh++){
    qf[qh][0] = *(const bf16x8*)(Qb + (qh*16 + fr)*DK + kg*8);
    qf[qh][1] = *(const bf16x8*)(Qb + (qh*16 + fr)*DK + 32 + kg*8);
  }

  f32x4 o[2][4];
#pragma unroll
  for (int qh = 0; qh < 2; qh++)
#pragma unroll
    for (int nd = 0; nd < 4; nd++) o[qh][nd] = f32x4{0.f,0.f,0.f,0.f};
  float mr[2] = {-1e30f, -1e30f};
  float lr[2] = {0.f, 0.f};

  for (int kt = 0; kt < SEQ; kt += 64){
    // ---- QK^T (swapped): K-frags shared by both q-subtiles
    f32x4 s[2][4];
#pragma unroll
    for (int n = 0; n < 4; n++){
      const unsigned short* kp = Kb + (size_t)(kt + n*16)*DK;
      bf16x8 k0 = *(const bf16x8*)kp;
      bf16x8 k1 = *(const bf16x8*)(kp + 32);
#pragma unroll
      for (int qh = 0; qh < 2; qh++){
        f32x4 z = f32x4{0.f,0.f,0.f,0.f};
        z         = __builtin_amdgcn_mfma_f32_16x16x32_bf16(k0, qf[qh][0], z, 0, 0, 0);
        s[qh][n]  = __builtin_amdgcn_mfma_f32_16x16x32_bf16(k1, qf[qh][1], s[qh][n] = z, 0, 0, 0);
      }
    }

    // ---- online softmax per q-subtile (all per-lane; q = fr)
    unsigned pk[2][4][2];
#pragma unroll
    for (int qh = 0; qh < 2; qh++){
      float tm = -1e30f;
#pragma unroll
      for (int n = 0; n < 4; n++)
#pragma unroll
        for (int r = 0; r < 4; r++) tm = fmaxf(tm, s[qh][n][r]);
      tm = fmaxf(tm, __shfl_xor(tm, 16));
      tm = fmaxf(tm, __shfl_xor(tm, 32));
      const bool defer = __all(tm - mr[qh] <= 8.0f);   // T13, wave-uniform
      float aal = 1.0f;
      if (!defer){
        const float mn = fmaxf(mr[qh], tm);
        aal = exp2f(mr[qh] - mn);
        mr[qh] = mn;
      }
      float p[4][4];
      float rs = 0.f;
#pragma unroll
      for (int n = 0; n < 4; n++)
#pragma unroll
        for (int r = 0; r < 4; r++){
          p[n][r] = exp2f(s[qh][n][r] - mr[qh]);
          rs += p[n][r];
        }
      rs += __shfl_xor(rs, 16);
      rs += __shfl_xor(rs, 32);
      lr[qh] = lr[qh]*aal + rs;
      if (!defer){
        f32x4 alv;
#pragma unroll
        for (int r = 0; r < 4; r++) alv[r] = __shfl(aal, kg*4 + r, 64);
#pragma unroll
        for (int nd = 0; nd < 4; nd++) o[qh][nd] *= alv;
      }
#pragma unroll
      for (int n = 0; n < 4; n++){
        pk[qh][n][0] = cvt_pk_bf16(p[n][0], p[n][1]);
        pk[qh][n][1] = cvt_pk_bf16(p[n][2], p[n][3]);
      }
    }

    // ---- PV via mfma_16x16x16: A = P (direct from regs), B = V^T slices (8B loads)
#pragma unroll
    for (int nd = 0; nd < 4; nd++){
      const unsigned short* vp = Vb + (size_t)(nd*16 + fr)*SEQ + kt;
      s16x4 vf[4];
#pragma unroll
      for (int ks = 0; ks < 4; ks++) vf[ks] = *(const s16x4*)(vp + ks*16);
#pragma unroll
      for (int ks = 0; ks < 4; ks++){
#pragma unroll
        for (int qh = 0; qh < 2; qh++){
          union { u32x2 u; s16x4 s; } pa;
          pa.u = u32x2{pk[qh][ks][0], pk[qh][ks][1]};
          o[qh][nd] = mfma16(pa.s, vf[ks], o[qh][nd]);
        }
      }
    }
  }

  // ---- epilogue: attn[b, s, h*64+d], divide by (l + 1e-10) per reference
  const int b = bh >> 4, h = bh & (NH-1);
#pragma unroll
  for (int qh = 0; qh < 2; qh++){
    const float invl = 1.f / (lr[qh] + 1e-10f);
    f32x4 iv;
#pragma unroll
    for (int r = 0; r < 4; r++) iv[r] = __shfl(invl, kg*4 + r, 64);
#pragma unroll
    for (int r = 0; r < 4; r++){
      const int srow = qt + qh*16 + kg*4 + r;
      const size_t base = ((size_t)b*SEQ + srow)*DMODEL + (size_t)h*DK;
#pragma unroll
      for (int nd = 0; nd < 4; nd++)
        attnO[base + nd*16 + fr] = f2bf(o[qh][nd][r] * iv[r]);
    }
  }
}

extern "C" void kernel_launch(void* const* d_in, const int* in_sizes, int n_in,
                              void* d_out, int out_size, void* d_ws, size_t ws_size,
                              hipStream_t stream)
{
  const float* q  = (const float*)d_in[0];
  const float* k  = (const float*)d_in[1];
  const float* v  = (const float*)d_in[2];
  const float* Wq = (const float*)d_in[3];
  const float* bq = (const float*)d_in[4];
  const float* Wk = (const float*)d_in[5];
  const float* bk = (const float*)d_in[6];
  const float* Wv = (const float*)d_in[7];
  const float* bv = (const float*)d_in[8];
  const float* Wo = (const float*)d_in[9];
  const float* bo = (const float*)d_in[10];

  char* ws = (char*)d_ws;
  const size_t WSZ = (size_t)DMODEL*DMODEL*2;   // 2 MB per weight (bf16)
  const size_t SZ  = (size_t)MTOT*DMODEL*2;     // 16 MB per token matrix (bf16)
  unsigned short* wqb   = (unsigned short*)(ws);
  unsigned short* wkb   = (unsigned short*)(ws + WSZ);
  unsigned short* wvb   = (unsigned short*)(ws + 2*WSZ);
  unsigned short* wob   = (unsigned short*)(ws + 3*WSZ);
  unsigned short* Qh    = (unsigned short*)(ws + 4*WSZ);
  unsigned short* Kh    = (unsigned short*)(ws + 4*WSZ + SZ);
  unsigned short* VTh   = (unsigned short*)(ws + 4*WSZ + 2*SZ);
  unsigned short* attnB = (unsigned short*)(ws + 4*WSZ + 3*SZ);

  const int n4 = DMODEL*DMODEL/4;
  cvt_kernel<<<n4/256, 256, 0, stream>>>(Wq, wqb, n4);
  cvt_kernel<<<n4/256, 256, 0, stream>>>(Wk, wkb, n4);
  cvt_kernel<<<n4/256, 256, 0, stream>>>(Wv, wvb, n4);
  cvt_kernel<<<n4/256, 256, 0, stream>>>(Wo, wob, n4);

  dim3 gproj(DMODEL/128, MTOT/128);   // (8, 64)
  // Q pre-scaled by log2(e)/sqrt(64) so attention can use exp2
  gemm_bt<0,1><<<gproj, 256, 0, stream>>>(q, wqb, bq, Qh, 0.125f*1.44269504088896f);
  gemm_bt<0,1><<<gproj, 256, 0, stream>>>(k, wkb, bk, Kh, 1.0f);
  gemm_bt<1,1><<<gproj, 256, 0, stream>>>(v, wvb, bv, VTh, 1.0f);

  attn_kernel<<<1024, 256, 0, stream>>>(Qh, Kh, VTh, attnB);

  gemm_bt<2,0><<<gproj, 256, 0, stream>>>(attnB, wob, bo, d_out, 1.0f);
}

// Round 4
// 510.251 us; speedup vs baseline: 1.0563x; 1.0563x over previous
//
#include <hip/hip_runtime.h>

#define DMODEL 1024
#define NH 16
#define DK 64
#define NB 4
#define SEQ 2048
#define MTOT (NB*SEQ)

typedef __attribute__((ext_vector_type(8))) short bf16x8;
typedef __attribute__((ext_vector_type(4))) short s16x4;
typedef __attribute__((ext_vector_type(4))) float f32x4;
typedef __attribute__((ext_vector_type(4))) float f4;
typedef __attribute__((ext_vector_type(4))) unsigned short us4;
typedef __attribute__((ext_vector_type(8))) unsigned short us8;
typedef __attribute__((ext_vector_type(2))) unsigned int u32x2;
typedef const __attribute__((address_space(1))) void* as1cv;
typedef __attribute__((address_space(3))) void* as3v;

__device__ __forceinline__ unsigned short f2bf(float f){
  union { float f; unsigned u; } v; v.f = f;
  unsigned r = v.u + 0x7FFFu + ((v.u >> 16) & 1u);   // RNE
  return (unsigned short)(r >> 16);
}

__device__ __forceinline__ unsigned cvt_pk_bf16(float lo, float hi){
  unsigned r;
  asm("v_cvt_pk_bf16_f32 %0, %1, %2" : "=v"(r) : "v"(lo), "v"(hi));
  return r;
}

// K=16 bf16 MFMA: A[row=lane&15][k=(lane>>4)*4+j], B[k=(lane>>4)*4+j][col=lane&15]
__device__ __forceinline__ f32x4 mfma16(s16x4 a, s16x4 b, f32x4 c){
#if __has_builtin(__builtin_amdgcn_mfma_f32_16x16x16bf16_1k)
  return __builtin_amdgcn_mfma_f32_16x16x16bf16_1k(a, b, c, 0, 0, 0);
#else
  asm("v_mfma_f32_16x16x16_bf16 %0, %1, %2, %0" : "+v"(c) : "v"(a), "v"(b));
  return c;
#endif
}

// ---------------- fp32 -> bf16 convert (weights) ----------------
__global__ __launch_bounds__(256) void cvt_kernel(const float* __restrict__ src,
                                                  unsigned short* __restrict__ dst, int n4){
  int i = blockIdx.x*256 + threadIdx.x;
  if (i >= n4) return;
  f4 f = ((const f4*)src)[i];
  us4 o;
  o.x = f2bf(f.x); o.y = f2bf(f.y); o.z = f2bf(f.z); o.w = f2bf(f.w);
  ((us4*)dst)[i] = o;
}

// ---------------- GEMM: C = A @ B^T + bias ----------------
// A: [M=8192, K=1024] fp32 (AF32=1, reg-staged+converted) or bf16 (AF32=0, global_load_lds)
// B: [N=1024, K=1024] bf16 (torch Linear weight layout)
// MODE 0: dst bf16 in [B,H,S,DK] layout, value = (acc+bias)*scale
// MODE 1: dst bf16 in [B,H,DK,S] (transposed) layout, value = acc + bias
// MODE 2: dst fp32 [M, N], value = acc + bias
template<int MODE, int AF32>
__global__ __launch_bounds__(256) void gemm_bt(const void* __restrict__ Aptr,
    const unsigned short* __restrict__ Bw, const float* __restrict__ bias,
    void* __restrict__ dst, float scale)
{
  __shared__ __align__(16) unsigned short sA[128*32];
  __shared__ __align__(16) unsigned short sB[128*32];
  const int tid = threadIdx.x;
  const int lane = tid & 63;
  const int w = tid >> 6;
  const int m0 = blockIdx.y * 128;
  const int n0 = blockIdx.x * 128;
  const int fr = lane & 15;
  const int kg = lane >> 4;
  const int msub = (w & 1) * 64;
  const int nsub = (w >> 1) * 64;

  f32x4 acc[4][4];
#pragma unroll
  for (int i = 0; i < 4; i++)
#pragma unroll
    for (int j = 0; j < 4; j++) acc[i][j] = f32x4{0.f,0.f,0.f,0.f};

  for (int kt = 0; kt < DMODEL; kt += 32){
#pragma unroll
    for (int j = 0; j < 2; j++){
      const int idx = j*256 + tid;
      const int row = idx >> 2;
      const int cg  = (idx & 3) << 3;
      if (AF32){
        const float* ap = (const float*)Aptr + (size_t)(m0+row)*DMODEL + kt + cg;
        f4 f0 = *(const f4*)ap;
        f4 f1 = *(const f4*)(ap + 4);
        us8 o;
        o[0]=f2bf(f0.x); o[1]=f2bf(f0.y); o[2]=f2bf(f0.z); o[3]=f2bf(f0.w);
        o[4]=f2bf(f1.x); o[5]=f2bf(f1.y); o[6]=f2bf(f1.z); o[7]=f2bf(f1.w);
        *((us8*)sA + idx) = o;
      } else {
        const unsigned short* ap = (const unsigned short*)Aptr + (size_t)(m0+row)*DMODEL + kt + cg;
        __builtin_amdgcn_global_load_lds((as1cv)ap, (as3v)(&sA[(size_t)idx*8]), 16, 0, 0);
      }
      const unsigned short* bp = Bw + (size_t)(n0+row)*DMODEL + kt + cg;
      __builtin_amdgcn_global_load_lds((as1cv)bp, (as3v)(&sB[(size_t)idx*8]), 16, 0, 0);
    }
    __syncthreads();
    bf16x8 af[4], bfr[4];
#pragma unroll
    for (int f = 0; f < 4; f++)
      af[f] = *(const bf16x8*)&sA[(msub + f*16 + fr)*32 + kg*8];
#pragma unroll
    for (int f = 0; f < 4; f++)
      bfr[f] = *(const bf16x8*)&sB[(nsub + f*16 + fr)*32 + kg*8];
#pragma unroll
    for (int i = 0; i < 4; i++)
#pragma unroll
      for (int j = 0; j < 4; j++)
        acc[i][j] = __builtin_amdgcn_mfma_f32_16x16x32_bf16(af[i], bfr[j], acc[i][j], 0, 0, 0);
    __syncthreads();
  }

  // epilogue: C/D layout col = lane&15, row = (lane>>4)*4 + r  [m89-verified]
#pragma unroll
  for (int i = 0; i < 4; i++){
#pragma unroll
    for (int j = 0; j < 4; j++){
      const int n = n0 + nsub + j*16 + fr;
      const float bv = bias[n];
      if (MODE == 1){
        // V^T layout: [(b*NH+h)*DK + d][s], 4 consecutive s per lane -> us4 store
        const int m = m0 + msub + i*16 + kg*4;
        const int b = m >> 11, s = m & (SEQ-1);
        const int h = n >> 6,  d = n & (DK-1);
        us4 pk;
#pragma unroll
        for (int r = 0; r < 4; r++) pk[r] = f2bf(acc[i][j][r] + bv);
        *(us4*)&((unsigned short*)dst)[((size_t)(b*NH+h)*DK + d)*SEQ + s] = pk;
      } else {
#pragma unroll
        for (int r = 0; r < 4; r++){
          const int m = m0 + msub + i*16 + kg*4 + r;
          float vacc = acc[i][j][r] + bv;
          if (MODE == 2){
            ((float*)dst)[(size_t)m*DMODEL + n] = vacc;
          } else {
            const int b = m >> 11, s = m & (SEQ-1);
            const int h = n >> 6,  d = n & (DK-1);
            ((unsigned short*)dst)[((size_t)(b*NH + h)*SEQ + s)*DK + d] = f2bf(vacc * scale);
          }
        }
      }
    }
  }
}

// ---------------- flash attention (LDS-free, register-pipelined) ----------------
// grid 1024 blocks x 256 threads = 4 independent waves; wave owns 32 q-rows (2 subtiles).
// Q pre-scaled by log2(e)/sqrt(DK). K in [B,H,S,DK] bf16; V^T in [B,H,DK,S] bf16.
// Swapped QK^T (mfma(K,Q)): lane holds S^T: q = lane&15, key = n*16 + (lane>>4)*4 + r.
// That register layout IS the A-fragment of mfma_16x16x16, so PV needs no redistribution.
// Pipelining: V(t) issued at tile top (used ~500cy later); K(t+1) issued mid-tile.
__global__ __launch_bounds__(256, 3) void attn_kernel(const unsigned short* __restrict__ Qh,
    const unsigned short* __restrict__ Kh, const unsigned short* __restrict__ VTh,
    unsigned short* __restrict__ attnO)
{
  const int tid = threadIdx.x;
  const int lane = tid & 63;
  const int w = tid >> 6;
  const int fr = lane & 15;
  const int kg = lane >> 4;
  // XCD-aware swizzle (bijective: 1024 % 8 == 0)
  const int bid = blockIdx.x;
  const int swz = (bid & 7) * 128 + (bid >> 3);
  const int bh = swz >> 4;                 // 16 blocks per (b,h)
  const int qt = (swz & 15) * 128 + w * 32;

  const unsigned short* Qb = Qh + ((size_t)bh*SEQ + qt)*DK;
  const unsigned short* Kb = Kh + (size_t)bh*SEQ*DK + (size_t)fr*DK + kg*8;
  const unsigned short* Vb = VTh + (size_t)bh*DK*SEQ + kg*4;

  bf16x8 qf[2][2];
#pragma unroll
  for (int qh = 0; qh < 2; qh++){
    qf[qh][0] = *(const bf16x8*)(Qb + (qh*16 + fr)*DK + kg*8);
    qf[qh][1] = *(const bf16x8*)(Qb + (qh*16 + fr)*DK + 32 + kg*8);
  }

  f32x4 o[2][4];
#pragma unroll
  for (int qh = 0; qh < 2; qh++)
#pragma unroll
    for (int nd = 0; nd < 4; nd++) o[qh][nd] = f32x4{0.f,0.f,0.f,0.f};
  float mr[2] = {-1e30f, -1e30f};
  float lr[2] = {0.f, 0.f};

  // prologue: K fragments for tile 0
  bf16x8 kc[8];
#pragma unroll
  for (int n = 0; n < 4; n++){
    kc[n*2+0] = *(const bf16x8*)(Kb + (size_t)(n*16)*DK);
    kc[n*2+1] = *(const bf16x8*)(Kb + (size_t)(n*16)*DK + 32);
  }

  for (int kt = 0; kt < SEQ; kt += 64){
    // ---- V tile loads, issued earliest (consumed after QK+softmax)
    s16x4 vf[4][4];
#pragma unroll
    for (int nd = 0; nd < 4; nd++){
      const unsigned short* vp = Vb + (size_t)(nd*16 + fr)*SEQ + kt;
#pragma unroll
      for (int ks = 0; ks < 4; ks++) vf[nd][ks] = *(const s16x4*)(vp + ks*16);
    }

    unsigned pk0[4][2], pk1[4][2];

    // ---- QK^T qh=0 (swapped): uses kc (prefetched last tile)
    f32x4 s0[4];
#pragma unroll
    for (int n = 0; n < 4; n++){
      f32x4 z = f32x4{0.f,0.f,0.f,0.f};
      z     = __builtin_amdgcn_mfma_f32_16x16x32_bf16(kc[n*2+0], qf[0][0], z, 0, 0, 0);
      s0[n] = __builtin_amdgcn_mfma_f32_16x16x32_bf16(kc[n*2+1], qf[0][1], z, 0, 0, 0);
    }
    // ---- softmax qh=0 (in place, then pack)
    {
      float tm = -1e30f;
#pragma unroll
      for (int n = 0; n < 4; n++)
#pragma unroll
        for (int r = 0; r < 4; r++) tm = fmaxf(tm, s0[n][r]);
      tm = fmaxf(tm, __shfl_xor(tm, 16));
      tm = fmaxf(tm, __shfl_xor(tm, 32));
      const bool defer = __all(tm - mr[0] <= 8.0f);   // T13, wave-uniform
      float aal = 1.0f;
      if (!defer){
        const float mn = fmaxf(mr[0], tm);
        aal = exp2f(mr[0] - mn);
        mr[0] = mn;
      }
      float rs = 0.f;
#pragma unroll
      for (int n = 0; n < 4; n++)
#pragma unroll
        for (int r = 0; r < 4; r++){
          s0[n][r] = exp2f(s0[n][r] - mr[0]);
          rs += s0[n][r];
        }
      rs += __shfl_xor(rs, 16);
      rs += __shfl_xor(rs, 32);
      lr[0] = lr[0]*aal + rs;
      if (!defer){
        f32x4 alv;
#pragma unroll
        for (int r = 0; r < 4; r++) alv[r] = __shfl(aal, kg*4 + r, 64);
#pragma unroll
        for (int nd = 0; nd < 4; nd++) o[0][nd] *= alv;
      }
#pragma unroll
      for (int n = 0; n < 4; n++){
        pk0[n][0] = cvt_pk_bf16(s0[n][0], s0[n][1]);
        pk0[n][1] = cvt_pk_bf16(s0[n][2], s0[n][3]);
      }
    }

    // ---- QK^T qh=1 (kc dies here)
    f32x4 s1[4];
#pragma unroll
    for (int n = 0; n < 4; n++){
      f32x4 z = f32x4{0.f,0.f,0.f,0.f};
      z     = __builtin_amdgcn_mfma_f32_16x16x32_bf16(kc[n*2+0], qf[1][0], z, 0, 0, 0);
      s1[n] = __builtin_amdgcn_mfma_f32_16x16x32_bf16(kc[n*2+1], qf[1][1], z, 0, 0, 0);
    }

    // ---- prefetch K for tile t+1 (registers of kc recycle; used next iter)
    const int ktn = (kt + 64 < SEQ) ? (kt + 64) : 0;   // clamped dummy on last tile
    bf16x8 kn[8];
#pragma unroll
    for (int n = 0; n < 4; n++){
      kn[n*2+0] = *(const bf16x8*)(Kb + (size_t)(ktn + n*16)*DK);
      kn[n*2+1] = *(const bf16x8*)(Kb + (size_t)(ktn + n*16)*DK + 32);
    }

    // ---- softmax qh=1
    {
      float tm = -1e30f;
#pragma unroll
      for (int n = 0; n < 4; n++)
#pragma unroll
        for (int r = 0; r < 4; r++) tm = fmaxf(tm, s1[n][r]);
      tm = fmaxf(tm, __shfl_xor(tm, 16));
      tm = fmaxf(tm, __shfl_xor(tm, 32));
      const bool defer = __all(tm - mr[1] <= 8.0f);
      float aal = 1.0f;
      if (!defer){
        const float mn = fmaxf(mr[1], tm);
        aal = exp2f(mr[1] - mn);
        mr[1] = mn;
      }
      float rs = 0.f;
#pragma unroll
      for (int n = 0; n < 4; n++)
#pragma unroll
        for (int r = 0; r < 4; r++){
          s1[n][r] = exp2f(s1[n][r] - mr[1]);
          rs += s1[n][r];
        }
      rs += __shfl_xor(rs, 16);
      rs += __shfl_xor(rs, 32);
      lr[1] = lr[1]*aal + rs;
      if (!defer){
        f32x4 alv;
#pragma unroll
        for (int r = 0; r < 4; r++) alv[r] = __shfl(aal, kg*4 + r, 64);
#pragma unroll
        for (int nd = 0; nd < 4; nd++) o[1][nd] *= alv;
      }
#pragma unroll
      for (int n = 0; n < 4; n++){
        pk1[n][0] = cvt_pk_bf16(s1[n][0], s1[n][1]);
        pk1[n][1] = cvt_pk_bf16(s1[n][2], s1[n][3]);
      }
    }

    // ---- PV via mfma_16x16x16: A = P (direct from regs), B = V^T slices (vf, long-issued)
#pragma unroll
    for (int nd = 0; nd < 4; nd++){
#pragma unroll
      for (int ks = 0; ks < 4; ks++){
        union { u32x2 u; s16x4 s; } a0, a1;
        a0.u = u32x2{pk0[ks][0], pk0[ks][1]};
        a1.u = u32x2{pk1[ks][0], pk1[ks][1]};
        o[0][nd] = mfma16(a0.s, vf[nd][ks], o[0][nd]);
        o[1][nd] = mfma16(a1.s, vf[nd][ks], o[1][nd]);
      }
    }

    // ---- rotate K buffers
#pragma unroll
    for (int i = 0; i < 8; i++) kc[i] = kn[i];
  }

  // ---- epilogue: attn[b, s, h*64+d], divide by (l + 1e-10) per reference
  const int b = bh >> 4, h = bh & (NH-1);
#pragma unroll
  for (int qh = 0; qh < 2; qh++){
    const float invl = 1.f / (lr[qh] + 1e-10f);
    f32x4 iv;
#pragma unroll
    for (int r = 0; r < 4; r++) iv[r] = __shfl(invl, kg*4 + r, 64);
#pragma unroll
    for (int r = 0; r < 4; r++){
      const int srow = qt + qh*16 + kg*4 + r;
      const size_t base = ((size_t)b*SEQ + srow)*DMODEL + (size_t)h*DK;
#pragma unroll
      for (int nd = 0; nd < 4; nd++)
        attnO[base + nd*16 + fr] = f2bf(o[qh][nd][r] * iv[r]);
    }
  }
}

extern "C" void kernel_launch(void* const* d_in, const int* in_sizes, int n_in,
                              void* d_out, int out_size, void* d_ws, size_t ws_size,
                              hipStream_t stream)
{
  const float* q  = (const float*)d_in[0];
  const float* k  = (const float*)d_in[1];
  const float* v  = (const float*)d_in[2];
  const float* Wq = (const float*)d_in[3];
  const float* bq = (const float*)d_in[4];
  const float* Wk = (const float*)d_in[5];
  const float* bk = (const float*)d_in[6];
  const float* Wv = (const float*)d_in[7];
  const float* bv = (const float*)d_in[8];
  const float* Wo = (const float*)d_in[9];
  const float* bo = (const float*)d_in[10];

  char* ws = (char*)d_ws;
  const size_t WSZ = (size_t)DMODEL*DMODEL*2;   // 2 MB per weight (bf16)
  const size_t SZ  = (size_t)MTOT*DMODEL*2;     // 16 MB per token matrix (bf16)
  unsigned short* wqb   = (unsigned short*)(ws);
  unsigned short* wkb   = (unsigned short*)(ws + WSZ);
  unsigned short* wvb   = (unsigned short*)(ws + 2*WSZ);
  unsigned short* wob   = (unsigned short*)(ws + 3*WSZ);
  unsigned short* Qh    = (unsigned short*)(ws + 4*WSZ);
  unsigned short* Kh    = (unsigned short*)(ws + 4*WSZ + SZ);
  unsigned short* VTh   = (unsigned short*)(ws + 4*WSZ + 2*SZ);
  unsigned short* attnB = (unsigned short*)(ws + 4*WSZ + 3*SZ);

  const int n4 = DMODEL*DMODEL/4;
  cvt_kernel<<<n4/256, 256, 0, stream>>>(Wq, wqb, n4);
  cvt_kernel<<<n4/256, 256, 0, stream>>>(Wk, wkb, n4);
  cvt_kernel<<<n4/256, 256, 0, stream>>>(Wv, wvb, n4);
  cvt_kernel<<<n4/256, 256, 0, stream>>>(Wo, wob, n4);

  dim3 gproj(DMODEL/128, MTOT/128);   // (8, 64)
  // Q pre-scaled by log2(e)/sqrt(64) so attention can use exp2
  gemm_bt<0,1><<<gproj, 256, 0, stream>>>(q, wqb, bq, Qh, 0.125f*1.44269504088896f);
  gemm_bt<0,1><<<gproj, 256, 0, stream>>>(k, wkb, bk, Kh, 1.0f);
  gemm_bt<1,1><<<gproj, 256, 0, stream>>>(v, wvb, bv, VTh, 1.0f);

  attn_kernel<<<1024, 256, 0, stream>>>(Qh, Kh, VTh, attnB);

  gemm_bt<2,0><<<gproj, 256, 0, stream>>>(attnB, wob, bo, d_out, 1.0f);
}